// Round 16
// baseline (127.025 us; speedup 1.0000x reference)
//
#include <hip/hip_runtime.h>
#include <hip/hip_bf16.h>

// Problem constants
#define SS 2048
#define BB 4
#define DD 256
#define HH 8
#define HDD 32
#define FFD 2048
#define MM (SS*BB)   // 8192 rows

typedef __attribute__((ext_vector_type(8))) __bf16 bf16x8;
typedef __attribute__((ext_vector_type(2))) __bf16 bf16x2;
typedef __attribute__((ext_vector_type(8))) short short8;
typedef __attribute__((ext_vector_type(4))) short short4v;
typedef __attribute__((ext_vector_type(4))) float f32x4;
typedef __attribute__((ext_vector_type(16))) float f32x16;
typedef __attribute__((ext_vector_type(2))) unsigned uint2v;
typedef __attribute__((ext_vector_type(4))) unsigned uint4v;

__device__ __forceinline__ unsigned short f2bf(float f) {
  union { float f; unsigned u; } v; v.f = f;
  unsigned r = v.u + 0x7fffu + ((v.u >> 16) & 1u);
  return (unsigned short)(r >> 16);
}

__device__ __forceinline__ float bf2f(short s) {
  union { float f; unsigned u; } v;
  v.u = ((unsigned)(unsigned short)s) << 16;
  return v.f;
}

__device__ __forceinline__ unsigned pk2(float a, float b) {
  bf16x2 t; t[0] = (__bf16)a; t[1] = (__bf16)b;
  return __builtin_bit_cast(unsigned, t);
}

__device__ __forceinline__ void gload16(const void* g, void* l) {
  __builtin_amdgcn_global_load_lds(
      (const __attribute__((address_space(1))) void*)g,
      (__attribute__((address_space(3))) void*)l, 16, 0, 0);
}

// ---------------- weight converts + LN(features), one launch ----------------
// grid (2048, 5): y<4 -> one weight convert each; y==4 -> LN1.
__global__ __launch_bounds__(256)
void cvt_ln(const float* __restrict__ a, const float* __restrict__ b,
            const float* __restrict__ c, const float* __restrict__ d,
            short* __restrict__ oa, short* __restrict__ ob,
            short* __restrict__ oc, short* __restrict__ od,
            const float* __restrict__ feat,
            const float* __restrict__ gam, const float* __restrict__ bet,
            float* __restrict__ lnf, short* __restrict__ lnb)
{
  const int y = blockIdx.y;
  if (y < 4) {
    const float* in; short* out; int n4;
    if (y == 0)      { in = a; out = oa; n4 = 768 * 256 / 4; }
    else if (y == 1) { in = b; out = ob; n4 = 256 * 256 / 4; }
    else if (y == 2) { in = c; out = oc; n4 = 2048 * 256 / 4; }
    else             { in = d; out = od; n4 = 2048 * 256 / 4; }
    const int i = blockIdx.x * 256 + threadIdx.x;
    if (i < n4) {
      float4 x = ((const float4*)in)[i];
      short4v o = { (short)f2bf(x.x), (short)f2bf(x.y), (short)f2bf(x.z), (short)f2bf(x.w) };
      ((short4v*)out)[i] = o;
    }
    return;
  }
  // LN1
  const int w = threadIdx.x >> 6, l = threadIdx.x & 63;
  const size_t row = (size_t)blockIdx.x * 4 + w;
  float4 x = *(const float4*)&feat[row * 256 + l * 4];
  float sum = x.x + x.y + x.z + x.w;
  float sq  = x.x*x.x + x.y*x.y + x.z*x.z + x.w*x.w;
#pragma unroll
  for (int off = 32; off > 0; off >>= 1) {
    sum += __shfl_xor(sum, off);
    sq  += __shfl_xor(sq, off);
  }
  const float mu = sum * (1.f / 256.f);
  const float rs = rsqrtf(sq * (1.f / 256.f) - mu * mu + 1e-5f);
  const float4 g4 = *(const float4*)&gam[l * 4];
  const float4 b4 = *(const float4*)&bet[l * 4];
  const float y0 = (x.x - mu) * rs * g4.x + b4.x;
  const float y1 = (x.y - mu) * rs * g4.y + b4.y;
  const float y2 = (x.z - mu) * rs * g4.z + b4.z;
  const float y3 = (x.w - mu) * rs * g4.w + b4.w;
  float4 o; o.x = y0; o.y = y1; o.z = y2; o.w = y3;
  *(float4*)&lnf[row * 256 + l * 4] = o;
  short4v ob2 = { (short)f2bf(y0), (short)f2bf(y1), (short)f2bf(y2), (short)f2bf(y3) };
  *(short4v*)&lnb[row * 256 + l * 4] = ob2;
}

// ---------------- LayerNorm over D=256, one wave per row ----------------
// BFI: xb/xc are bf16 (short*) instead of f32.
template<int NIN, int WF, int WBF, int BFI>
__global__ __launch_bounds__(256)
void ln_kernel(const float* __restrict__ xa, const void* __restrict__ xb,
               const void* __restrict__ xc,
               const float* __restrict__ gam, const float* __restrict__ bet,
               float* __restrict__ outf, short* __restrict__ outb)
{
  const int w = threadIdx.x >> 6, l = threadIdx.x & 63;
  const size_t row = (size_t)blockIdx.x * 4 + w;
  float4 x = *(const float4*)&xa[row * 256 + l * 4];
  if (NIN >= 2) {
    if (BFI) {
      const short4v yb = *(const short4v*)&((const short*)xb)[row * 256 + l * 4];
      x.x += bf2f(yb[0]); x.y += bf2f(yb[1]); x.z += bf2f(yb[2]); x.w += bf2f(yb[3]);
    } else {
      const float4 yv = *(const float4*)&((const float*)xb)[row * 256 + l * 4];
      x.x += yv.x; x.y += yv.y; x.z += yv.z; x.w += yv.w;
    }
  }
  if (NIN >= 3) {
    if (BFI) {
      const short4v yc = *(const short4v*)&((const short*)xc)[row * 256 + l * 4];
      x.x += bf2f(yc[0]); x.y += bf2f(yc[1]); x.z += bf2f(yc[2]); x.w += bf2f(yc[3]);
    } else {
      const float4 yv = *(const float4*)&((const float*)xc)[row * 256 + l * 4];
      x.x += yv.x; x.y += yv.y; x.z += yv.z; x.w += yv.w;
    }
  }
  float sum = x.x + x.y + x.z + x.w;
  float sq  = x.x*x.x + x.y*x.y + x.z*x.z + x.w*x.w;
#pragma unroll
  for (int off = 32; off > 0; off >>= 1) {
    sum += __shfl_xor(sum, off);
    sq  += __shfl_xor(sq, off);
  }
  const float mu = sum * (1.f / 256.f);
  const float rs = rsqrtf(sq * (1.f / 256.f) - mu * mu + 1e-5f);
  const float4 g4 = *(const float4*)&gam[l * 4];
  const float4 b4 = *(const float4*)&bet[l * 4];
  const float y0 = (x.x - mu) * rs * g4.x + b4.x;
  const float y1 = (x.y - mu) * rs * g4.y + b4.y;
  const float y2 = (x.z - mu) * rs * g4.z + b4.z;
  const float y3 = (x.w - mu) * rs * g4.w + b4.w;
  if (WF) {
    float4 o; o.x = y0; o.y = y1; o.z = y2; o.w = y3;
    *(float4*)&outf[row * 256 + l * 4] = o;
  }
  if (WBF) {
    short4v o = { (short)f2bf(y0), (short)f2bf(y1), (short)f2bf(y2), (short)f2bf(y3) };
    *(short4v*)&outb[row * 256 + l * 4] = o;
  }
}

// ---------------- bf16 GEMM, C = A(MxK) * W(NxK)^T + bias, BMxBN tile, BK=64 ----
// Double-buffered LDS, 2-phase: stage(t+1) issued before compute(t).
// LDS rows are 128B -> XOR-swizzled (chunk ^= row&7) on BOTH the global source
// (pre-swizzle, since global_load_lds writes linearly) and the ds_read side.
// KW != 0: W's K-stride (stacked-partial trick: W column index wraps mod KW).
// EPI 0: qkv scatter (q scaled by 2log2e/sqrt(hd); q/k [bh][s][hd], v
//        INTERLEAVED [bh][s/8][hd][s%8] so attn B-frags are 16B vector loads)
// EPI 1: f32 out (out_proj)
// EPI 2: relu, bf16 out (ff1)
// EPI 3: bf16 out, split-K via blockIdx.z (partial 1 -> out2, bias on kz==0)
template<int EPI, int BM, int BN, int KW>
__global__ __launch_bounds__(256)
void gemm_bt(const short* __restrict__ A, const short* __restrict__ W,
             const float* __restrict__ bias, void* __restrict__ out,
             void* __restrict__ out2, int K, int N, int Ksub)
{
  __shared__ short sA[2][BM * 64];
  __shared__ short sB[2][BN * 64];
  const int tid = threadIdx.x;
  const int l  = tid & 63;
  const int w  = tid >> 6;
  const int wr = w >> 1, wc = w & 1;
  const int lr = l & 15, lg = l >> 4;
  const long row0 = (long)blockIdx.y * BM;
  const long col0 = (long)blockIdx.x * BN;
  const int kz = blockIdx.z;
  const int kbeg = kz * Ksub;
  const int ldsw = (tid & ~63) * 16;   // wave-uniform LDS byte base
  constexpr int MR = BM / 32, NR = BN / 32;
  f32x4 acc[MR][NR] = {};
  const int nt = Ksub / 64;

  auto stage = [&](int buf, int k0) {
#pragma unroll
    for (int i = 0; i < BM / 32; i++) {
      const int o = (i * 256 + tid) * 16;     // byte offset in BM x 128B tile
      const int r = o >> 7;                   // row (128B rows: 64 bf16)
      const int cg = ((o >> 4) & 7) ^ (r & 7);// pre-swizzled global 16B chunk
      gload16((const char*)A + ((row0 + r) * (long)K + k0) * 2 + cg * 16,
              (char*)sA[buf] + i * 4096 + ldsw);
    }
    const long wstride = KW ? KW : K;
    const long wk = KW ? (k0 & (KW - 1)) : k0;
#pragma unroll
    for (int i = 0; i < BN / 32; i++) {
      const int o = (i * 256 + tid) * 16;
      const int r = o >> 7;
      const int cg = ((o >> 4) & 7) ^ (r & 7);
      gload16((const char*)W + ((col0 + r) * wstride + wk) * 2 + cg * 16,
              (char*)sB[buf] + i * 4096 + ldsw);
    }
  };

  stage(0, kbeg);
  __syncthreads();
  int cur = 0;
  for (int t = 0; t < nt; t++) {
    if (t + 1 < nt) stage(cur ^ 1, kbeg + (t + 1) * 64);
    bf16x8 af[MR][2], bw[NR][2];
#pragma unroll
    for (int m = 0; m < MR; m++)
#pragma unroll
      for (int kk = 0; kk < 2; kk++) {
        const int row = wr * (BM/2) + m * 16 + lr;
        af[m][kk] = *(const bf16x8*)&sA[cur][row * 64 + (((kk*4 + lg) ^ (lr & 7)) * 8)];
      }
#pragma unroll
    for (int n = 0; n < NR; n++)
#pragma unroll
      for (int kk = 0; kk < 2; kk++) {
        const int row = wc * (BN/2) + n * 16 + lr;
        bw[n][kk] = *(const bf16x8*)&sB[cur][row * 64 + (((kk*4 + lg) ^ (lr & 7)) * 8)];
      }
#pragma unroll
    for (int kk = 0; kk < 2; kk++)
#pragma unroll
      for (int m = 0; m < MR; m++)
#pragma unroll
        for (int n = 0; n < NR; n++)
          acc[m][n] = __builtin_amdgcn_mfma_f32_16x16x32_bf16(af[m][kk], bw[n][kk], acc[m][n], 0, 0, 0);
    __syncthreads();
    cur ^= 1;
  }

#pragma unroll
  for (int m = 0; m < MR; m++) {
    const long rbase = row0 + wr * (BM/2) + m * 16 + lg * 4;
#pragma unroll
    for (int n = 0; n < NR; n++) {
      const long c = col0 + wc * (BN/2) + n * 16 + lr;
      const float bv = (EPI == 3 && kz) ? 0.f : bias[c];
#pragma unroll
      for (int j = 0; j < 4; j++) {
        const long r = rbase + j;
        float val = acc[m][n][j] + bv;
        if (EPI == 0) {
          const int part = (int)(c >> 8);
          const int cc = (int)(c & 255);
          const int h = cc >> 5, hd = cc & 31;
          const int bi = (int)(r & 3);
          const int s = (int)(r >> 2);
          const int bh = bi * HH + h;
          // q scale: (1/sqrt(32)) * 2*log2(e)  (activation uses exp2 directly)
          if (part == 0) val *= 0.51006972771029396f;
          size_t idx;
          if (part == 2) {  // V interleaved: [bh][s/8][hd][s%8]
            idx = (size_t)2 * (MM * DD) + (size_t)bh * (SS * HDD)
                + (size_t)(s >> 3) * (HDD * 8) + hd * 8 + (s & 7);
          } else {          // Q/K: [bh][s][hd]
            idx = (size_t)part * (MM * DD) + ((size_t)bh * SS + s) * HDD + hd;
          }
          ((short*)out)[idx] = (short)f2bf(val);
        } else if (EPI == 1) {
          ((float*)out)[(size_t)r * N + c] = val;
        } else if (EPI == 2) {
          ((short*)out)[(size_t)r * N + c] = (short)f2bf(fmaxf(val, 0.f));
        } else {
          short* op = kz ? (short*)out2 : (short*)out;
          op[(size_t)r * N + c] = (short)f2bf(val);
        }
      }
    }
  }
}

// ---------------- fused tanh-relu attention, 2-stage score pipeline ----------
// 32x32x16 MFMA, P fully in-register via cvt_pk + permlane32_swap.
// Software-pipelined one tile deep: QK^T of tile i+1 is issued BEFORE the
// act+PV of tile i, so the MFMA->act latency hides under the previous tile's
// ~300-cycle act+PV and act-VALU overlaps next tile's MFMAs. K loaded 2 tiles
// ahead, V 1 tile ahead (named buffers). V interleaved [s/8][d][s%8]: each
// 16-key B-frag is one 16B load. XCD-coherent flat grid (1024): all 32 blocks
// of a (b,h) on xcd = bh%8. 4 waves x 32 q; split-K x2; bf16 partials into
// stacked A' (8192 x 512) consumed by the K=512 out_proj GEMM.
__global__ __launch_bounds__(256)
void attn_kernel(const short* __restrict__ Qb, const short* __restrict__ Kb,
                 const short* __restrict__ Vb, short* __restrict__ Aout)
{
  const int tid = threadIdx.x;
  const int l = tid & 63, w = tid >> 6;
  const int q32 = l & 31, hf = l >> 5;        // lane col, lane half
  const int i = blockIdx.x;                   // 0..1023
  const int j = i >> 3;                       // 0..127 (per-XCD serial)
  const int p = (i & 7) + 8 * (j >> 5);       // bh: fixed residue mod 8
  const int rem = j & 31;
  const int q0 = (rem >> 1) * 128 + w * 32;   // q-block 0..15
  const int kz = rem & 1;                     // key half
  const int kbeg = kz * (SS / 2);
  const int kend = kbeg + SS / 2;
  const size_t base = (size_t)p * SS * HDD;
  const short* Q  = Qb + base;
  const short* Kp = Kb + base;
  const short* Vp = Vb + base;                // interleaved [s/8][d=32][s%8]

  // Q frags (B operand of QK^T): lane holds Q[q0+q32][kdim], slot k = hf*8+j
  const short* qrow = &Q[(size_t)(q0 + q32) * HDD];
  const bf16x8 qf0 = *(const bf16x8*)&qrow[hf * 8];        // kdim 0..15
  const bf16x8 qf1 = *(const bf16x8*)&qrow[16 + hf * 8];   // kdim 16..31

  const f32x16 fzero = {};
  f32x16 accA = {}, accB = {};   // O[q][d]: col=q32 is d, row q=(r&3)+8*(r>>2)+4*hf

  auto loadKr = [&](int t0, bf16x8& f0, bf16x8& f1) {
    const short* kr = &Kp[(size_t)(t0 + q32) * HDD];
    f0 = *(const bf16x8*)&kr[hf * 8];
    f1 = *(const bf16x8*)&kr[16 + hf * 8];
  };
  // V B-frag f: slot (hf,e) = V[t0 + f*16 + hf*8 + e][d=q32]; in the
  // interleaved layout that is 8 contiguous shorts at group (t0>>3)+2f+hf.
  auto loadVr = [&](int t0, bf16x8& f0, bf16x8& f1) {
    const short* vb = &Vp[(size_t)((t0 >> 3) + hf) * (HDD * 8) + q32 * 8];
    f0 = *(const bf16x8*)&vb[0];
    f1 = *(const bf16x8*)&vb[2 * (HDD * 8)];
  };
  auto qkt = [&](const bf16x8& k0, const bf16x8& k1) -> f32x16 {
    // scores D[key][q] over kdim=32 (pre-scaled by 2log2e/sqrt(32))
    f32x16 s = __builtin_amdgcn_mfma_f32_32x32x16_bf16(k0, qf0, fzero, 0, 0, 0);
    return __builtin_amdgcn_mfma_f32_32x32x16_bf16(k1, qf1, s, 0, 0, 0);
  };
  auto actpv = [&](const f32x16& s, const bf16x8& v0, const bf16x8& v1, f32x16& acc) {
    // relu(tanh(x)) = max(0, 1 - 2/(exp2(s)+1))
    float pv[16];
#pragma unroll
    for (int r = 0; r < 16; r++) {
      const float e = __builtin_amdgcn_exp2f(s[r]);
      pv[r] = fmaxf(1.f - 2.f * __builtin_amdgcn_rcpf(e + 1.f), 0.f);
    }
    unsigned X0 = pk2(pv[0], pv[1]),   X1 = pk2(pv[2], pv[3]);
    unsigned X2 = pk2(pv[4], pv[5]),   X3 = pk2(pv[6], pv[7]);
    unsigned X4 = pk2(pv[8], pv[9]),   X5 = pk2(pv[10], pv[11]);
    unsigned X6 = pk2(pv[12], pv[13]), X7 = pk2(pv[14], pv[15]);
    uint2v r02 = __builtin_amdgcn_permlane32_swap(X0, X2, false, false);
    uint2v r13 = __builtin_amdgcn_permlane32_swap(X1, X3, false, false);
    uint2v r46 = __builtin_amdgcn_permlane32_swap(X4, X6, false, false);
    uint2v r57 = __builtin_amdgcn_permlane32_swap(X5, X7, false, false);
    // P frags: lane q32 holds keys (slot k = 16f + hf*8 + e) -- valid A-frag
    const uint4v f0 = { r02[0], r13[0], r02[1], r13[1] };
    const uint4v f1 = { r46[0], r57[0], r46[1], r57[1] };
    const bf16x8 pa0 = __builtin_bit_cast(bf16x8, f0);
    const bf16x8 pa1 = __builtin_bit_cast(bf16x8, f1);
    // O[q][d] += P[q][k] * V[k][d]
    acc = __builtin_amdgcn_mfma_f32_32x32x16_bf16(pa0, v0, acc, 0, 0, 0);
    acc = __builtin_amdgcn_mfma_f32_32x32x16_bf16(pa1, v1, acc, 0, 0, 0);
  };

  bf16x8 kA0, kA1, kB0, kB1, vA0, vA1, vB0, vB1;
  f32x16 sA, sB;
  // Prologue: K 2 tiles ahead, V 1 tile ahead, first scores computed.
  loadKr(kbeg, kA0, kA1);
  loadKr(kbeg + 32, kB0, kB1);
  loadVr(kbeg, vA0, vA1);
  sA = qkt(kA0, kA1);

  for (int t0 = kbeg; t0 < kend; t0 += 64) {
    const int tA = (t0 + 64 < kend) ? t0 + 64 : kbeg;   // wrap = dummy work
    loadKr(tA, kA0, kA1);
    loadVr(t0 + 32, vB0, vB1);
    sB = qkt(kB0, kB1);          // tile t0+32 scores (K loaded last iter)
    actpv(sA, vA0, vA1, accA);   // finish tile t0
    const int tB = (t0 + 96 < kend) ? t0 + 96 : kbeg;
    loadKr(tB, kB0, kB1);
    loadVr(tA, vA0, vA1);
    sA = qkt(kA0, kA1);          // tile t0+64 scores (K loaded this iter)
    actpv(sB, vB0, vB1, accB);   // finish tile t0+32
  }

  const int bi = p >> 3, hh = p & 7;
  // A' row = s*BB+bi, K-stride 512; this lane owns column d = q32
  const size_t colo = (size_t)kz * DD + (size_t)hh * HDD + q32;
#pragma unroll
  for (int r = 0; r < 16; r++) {
    const int crow = (r & 3) + 8 * (r >> 2) + 4 * hf;
    Aout[((size_t)(q0 + crow) * BB + bi) * (2 * DD) + colo] =
        (short)f2bf(accA[r] + accB[r]);
  }
}

// ---------------- launch ----------------
extern "C" void kernel_launch(void* const* d_in, const int* in_sizes, int n_in,
                              void* d_out, int out_size, void* d_ws, size_t ws_size,
                              hipStream_t stream) {
  const float* features   = (const float*)d_in[0];
  const float* ln_g       = (const float*)d_in[1];
  const float* ln_b       = (const float*)d_in[2];
  const float* in_proj_w  = (const float*)d_in[3];
  const float* in_proj_b  = (const float*)d_in[4];
  const float* out_proj_w = (const float*)d_in[5];
  const float* out_proj_b = (const float*)d_in[6];
  const float* w1 = (const float*)d_in[7];
  const float* b1 = (const float*)d_in[8];
  const float* w2 = (const float*)d_in[9];
  const float* b2 = (const float*)d_in[10];

  char* ws = (char*)d_ws;
  const size_t MB = 1024 * 1024;
  // [0,8)   lnx_f
  // [8,12)  lnx_b
  // [12,24) qkv (q,k,vI)   -> [12,16) ffb ; [16,20) ffp1 ; [20,24) r1_b
  //         (proj f32 occupies [12,20) between out_proj and r1 LN)
  // [24,32) A' (attn stacked partials, bf16 8192x512) -> r1_f (after out_proj)
  // [32,64) h1
  // [64,~)  weights
  float* lnx_f  = (float*)(ws + 0);
  short* lnx_b  = (short*)(ws + 8 * MB);
  short* qkv    = (short*)(ws + 12 * MB);
  short* aprt   = (short*)(ws + 24 * MB);   // A' stacked attn partials (8MB)
  float* proj   = (float*)(ws + 12 * MB);
  short* r1_b   = (short*)(ws + 20 * MB);
  float* r1_f   = (float*)(ws + 24 * MB);
  short* h1     = (short*)(ws + 32 * MB);
  short* ffb    = (short*)(ws + 12 * MB);   // ff partial 0, bf16 (4MB)
  short* ffp1   = (short*)(ws + 16 * MB);   // ff partial 1, bf16 (4MB)
  short* wqkv_b = (short*)(ws + 64 * MB);
  short* wout_b = wqkv_b + 768 * 256;
  short* w1_b   = wout_b + 256 * 256;
  short* w2_b   = w1_b + 2048 * 256;

  // 1) weight converts + ln_x = LN(features), one launch
  cvt_ln<<<dim3(2048, 5), 256, 0, stream>>>(in_proj_w, out_proj_w, w1, w2,
                                            wqkv_b, wout_b, w1_b, w2_b,
                                            features, ln_g, ln_b, lnx_f, lnx_b);

  // 2) qkv = ln_x @ in_proj_w^T + b  (q/k per-(b,h) [s][hd], v interleaved)
  gemm_bt<0, 128, 64, 0><<<dim3(12, 64, 1), 256, 0, stream>>>(lnx_b, wqkv_b, in_proj_b, qkv, nullptr, 256, 768, 256);

  // 3) attention (relu(tanh(qk^T)) @ v), split-K x2, 2-stage score pipeline
  attn_kernel<<<dim3(1024, 1, 1), 256, 0, stream>>>(qkv, qkv + 2097152, qkv + 2 * 2097152, aprt);

  // 4) proj = (sum of A' partials) @ out_proj_w^T + b  [K=512, W wraps mod 256]
  gemm_bt<1, 64, 64, 256><<<dim3(4, 128, 1), 256, 0, stream>>>(aprt, wout_b, out_proj_b, proj, nullptr, 512, 256, 512);

  // 5) r1 = LN(ln_x + proj)
  ln_kernel<2, 1, 1, 0><<<2048, 256, 0, stream>>>(lnx_f, proj, nullptr, ln_g, ln_b, r1_f, r1_b);

  // 6) h1 = relu(r1 @ w1^T + b1)  [128x128 tile: 32 MFMA per barrier-pair]
  gemm_bt<2, 128, 128, 0><<<dim3(16, 64, 1), 256, 0, stream>>>(r1_b, w1_b, b1, h1, nullptr, 256, 2048, 256);

  // 7) ff = h1 @ w2^T + b2  (split-K x2: bf16 partials in ffb, ffp1)
  gemm_bt<3, 128, 64, 0><<<dim3(4, 64, 2), 256, 0, stream>>>(h1, w2_b, b2, ffb, ffp1, 2048, 256, 1024);

  // 8) out = LN(r1 + ff0 + ff1)   (bf16 partial inputs)
  ln_kernel<3, 1, 0, 1><<<2048, 256, 0, stream>>>(r1_f, ffb, ffp1, ln_g, ln_b, (float*)d_out, nullptr);
}

// Round 17
// 124.650 us; speedup vs baseline: 1.0190x; 1.0190x over previous
//
#include <hip/hip_runtime.h>
#include <hip/hip_bf16.h>

// Problem constants
#define SS 2048
#define BB 4
#define DD 256
#define HH 8
#define HDD 32
#define FFD 2048
#define MM (SS*BB)   // 8192 rows

typedef __attribute__((ext_vector_type(8))) __bf16 bf16x8;
typedef __attribute__((ext_vector_type(2))) __bf16 bf16x2;
typedef __attribute__((ext_vector_type(8))) short short8;
typedef __attribute__((ext_vector_type(4))) short short4v;
typedef __attribute__((ext_vector_type(4))) float f32x4;
typedef __attribute__((ext_vector_type(16))) float f32x16;
typedef __attribute__((ext_vector_type(2))) unsigned uint2v;
typedef __attribute__((ext_vector_type(4))) unsigned uint4v;

__device__ __forceinline__ unsigned short f2bf(float f) {
  union { float f; unsigned u; } v; v.f = f;
  unsigned r = v.u + 0x7fffu + ((v.u >> 16) & 1u);
  return (unsigned short)(r >> 16);
}

__device__ __forceinline__ float bf2f(short s) {
  union { float f; unsigned u; } v;
  v.u = ((unsigned)(unsigned short)s) << 16;
  return v.f;
}

__device__ __forceinline__ unsigned pk2(float a, float b) {
  bf16x2 t; t[0] = (__bf16)a; t[1] = (__bf16)b;
  return __builtin_bit_cast(unsigned, t);
}

__device__ __forceinline__ void gload16(const void* g, void* l) {
  __builtin_amdgcn_global_load_lds(
      (const __attribute__((address_space(1))) void*)g,
      (__attribute__((address_space(3))) void*)l, 16, 0, 0);
}

// ---------------- weight converts + LN(features), one launch ----------------
// grid (2048, 5): y<4 -> one weight convert each; y==4 -> LN1.
__global__ __launch_bounds__(256)
void cvt_ln(const float* __restrict__ a, const float* __restrict__ b,
            const float* __restrict__ c, const float* __restrict__ d,
            short* __restrict__ oa, short* __restrict__ ob,
            short* __restrict__ oc, short* __restrict__ od,
            const float* __restrict__ feat,
            const float* __restrict__ gam, const float* __restrict__ bet,
            float* __restrict__ lnf, short* __restrict__ lnb)
{
  const int y = blockIdx.y;
  if (y < 4) {
    const float* in; short* out; int n4;
    if (y == 0)      { in = a; out = oa; n4 = 768 * 256 / 4; }
    else if (y == 1) { in = b; out = ob; n4 = 256 * 256 / 4; }
    else if (y == 2) { in = c; out = oc; n4 = 2048 * 256 / 4; }
    else             { in = d; out = od; n4 = 2048 * 256 / 4; }
    const int i = blockIdx.x * 256 + threadIdx.x;
    if (i < n4) {
      float4 x = ((const float4*)in)[i];
      short4v o = { (short)f2bf(x.x), (short)f2bf(x.y), (short)f2bf(x.z), (short)f2bf(x.w) };
      ((short4v*)out)[i] = o;
    }
    return;
  }
  // LN1
  const int w = threadIdx.x >> 6, l = threadIdx.x & 63;
  const size_t row = (size_t)blockIdx.x * 4 + w;
  float4 x = *(const float4*)&feat[row * 256 + l * 4];
  float sum = x.x + x.y + x.z + x.w;
  float sq  = x.x*x.x + x.y*x.y + x.z*x.z + x.w*x.w;
#pragma unroll
  for (int off = 32; off > 0; off >>= 1) {
    sum += __shfl_xor(sum, off);
    sq  += __shfl_xor(sq, off);
  }
  const float mu = sum * (1.f / 256.f);
  const float rs = rsqrtf(sq * (1.f / 256.f) - mu * mu + 1e-5f);
  const float4 g4 = *(const float4*)&gam[l * 4];
  const float4 b4 = *(const float4*)&bet[l * 4];
  const float y0 = (x.x - mu) * rs * g4.x + b4.x;
  const float y1 = (x.y - mu) * rs * g4.y + b4.y;
  const float y2 = (x.z - mu) * rs * g4.z + b4.z;
  const float y3 = (x.w - mu) * rs * g4.w + b4.w;
  float4 o; o.x = y0; o.y = y1; o.z = y2; o.w = y3;
  *(float4*)&lnf[row * 256 + l * 4] = o;
  short4v ob2 = { (short)f2bf(y0), (short)f2bf(y1), (short)f2bf(y2), (short)f2bf(y3) };
  *(short4v*)&lnb[row * 256 + l * 4] = ob2;
}

// ---------------- LayerNorm over D=256, one wave per row ----------------
// BFI: xb/xc are bf16 (short*) instead of f32.
template<int NIN, int WF, int WBF, int BFI>
__global__ __launch_bounds__(256)
void ln_kernel(const float* __restrict__ xa, const void* __restrict__ xb,
               const void* __restrict__ xc,
               const float* __restrict__ gam, const float* __restrict__ bet,
               float* __restrict__ outf, short* __restrict__ outb)
{
  const int w = threadIdx.x >> 6, l = threadIdx.x & 63;
  const size_t row = (size_t)blockIdx.x * 4 + w;
  float4 x = *(const float4*)&xa[row * 256 + l * 4];
  if (NIN >= 2) {
    if (BFI) {
      const short4v yb = *(const short4v*)&((const short*)xb)[row * 256 + l * 4];
      x.x += bf2f(yb[0]); x.y += bf2f(yb[1]); x.z += bf2f(yb[2]); x.w += bf2f(yb[3]);
    } else {
      const float4 yv = *(const float4*)&((const float*)xb)[row * 256 + l * 4];
      x.x += yv.x; x.y += yv.y; x.z += yv.z; x.w += yv.w;
    }
  }
  if (NIN >= 3) {
    if (BFI) {
      const short4v yc = *(const short4v*)&((const short*)xc)[row * 256 + l * 4];
      x.x += bf2f(yc[0]); x.y += bf2f(yc[1]); x.z += bf2f(yc[2]); x.w += bf2f(yc[3]);
    } else {
      const float4 yv = *(const float4*)&((const float*)xc)[row * 256 + l * 4];
      x.x += yv.x; x.y += yv.y; x.z += yv.z; x.w += yv.w;
    }
  }
  float sum = x.x + x.y + x.z + x.w;
  float sq  = x.x*x.x + x.y*x.y + x.z*x.z + x.w*x.w;
#pragma unroll
  for (int off = 32; off > 0; off >>= 1) {
    sum += __shfl_xor(sum, off);
    sq  += __shfl_xor(sq, off);
  }
  const float mu = sum * (1.f / 256.f);
  const float rs = rsqrtf(sq * (1.f / 256.f) - mu * mu + 1e-5f);
  const float4 g4 = *(const float4*)&gam[l * 4];
  const float4 b4 = *(const float4*)&bet[l * 4];
  const float y0 = (x.x - mu) * rs * g4.x + b4.x;
  const float y1 = (x.y - mu) * rs * g4.y + b4.y;
  const float y2 = (x.z - mu) * rs * g4.z + b4.z;
  const float y3 = (x.w - mu) * rs * g4.w + b4.w;
  if (WF) {
    float4 o; o.x = y0; o.y = y1; o.z = y2; o.w = y3;
    *(float4*)&outf[row * 256 + l * 4] = o;
  }
  if (WBF) {
    short4v o = { (short)f2bf(y0), (short)f2bf(y1), (short)f2bf(y2), (short)f2bf(y3) };
    *(short4v*)&outb[row * 256 + l * 4] = o;
  }
}

// ---------------- bf16 GEMM, C = A(MxK) * W(NxK)^T + bias, BMxBN tile, BK=64 ----
// Double-buffered LDS, 2-phase: stage(t+1) issued before compute(t).
// LDS rows are 128B -> XOR-swizzled (chunk ^= row&7) on BOTH the global source
// (pre-swizzle, since global_load_lds writes linearly) and the ds_read side.
// KW != 0: W's K-stride (stacked-partial trick: W column index wraps mod KW).
// EPI 0: qkv scatter (q scaled by 2log2e/sqrt(hd); q/k [bh][s][hd], v
//        INTERLEAVED [bh][s/8][hd][s%8] so attn B-frags are 16B vector loads)
// EPI 1: f32 out (out_proj)
// EPI 2: relu, bf16 out (ff1)
// EPI 3: bf16 out, split-K via blockIdx.z (partial 1 -> out2, bias on kz==0)
template<int EPI, int BM, int BN, int KW>
__global__ __launch_bounds__(256)
void gemm_bt(const short* __restrict__ A, const short* __restrict__ W,
             const float* __restrict__ bias, void* __restrict__ out,
             void* __restrict__ out2, int K, int N, int Ksub)
{
  __shared__ short sA[2][BM * 64];
  __shared__ short sB[2][BN * 64];
  const int tid = threadIdx.x;
  const int l  = tid & 63;
  const int w  = tid >> 6;
  const int wr = w >> 1, wc = w & 1;
  const int lr = l & 15, lg = l >> 4;
  const long row0 = (long)blockIdx.y * BM;
  const long col0 = (long)blockIdx.x * BN;
  const int kz = blockIdx.z;
  const int kbeg = kz * Ksub;
  const int ldsw = (tid & ~63) * 16;   // wave-uniform LDS byte base
  constexpr int MR = BM / 32, NR = BN / 32;
  f32x4 acc[MR][NR] = {};
  const int nt = Ksub / 64;

  auto stage = [&](int buf, int k0) {
#pragma unroll
    for (int i = 0; i < BM / 32; i++) {
      const int o = (i * 256 + tid) * 16;     // byte offset in BM x 128B tile
      const int r = o >> 7;                   // row (128B rows: 64 bf16)
      const int cg = ((o >> 4) & 7) ^ (r & 7);// pre-swizzled global 16B chunk
      gload16((const char*)A + ((row0 + r) * (long)K + k0) * 2 + cg * 16,
              (char*)sA[buf] + i * 4096 + ldsw);
    }
    const long wstride = KW ? KW : K;
    const long wk = KW ? (k0 & (KW - 1)) : k0;
#pragma unroll
    for (int i = 0; i < BN / 32; i++) {
      const int o = (i * 256 + tid) * 16;
      const int r = o >> 7;
      const int cg = ((o >> 4) & 7) ^ (r & 7);
      gload16((const char*)W + ((col0 + r) * wstride + wk) * 2 + cg * 16,
              (char*)sB[buf] + i * 4096 + ldsw);
    }
  };

  stage(0, kbeg);
  __syncthreads();
  int cur = 0;
  for (int t = 0; t < nt; t++) {
    if (t + 1 < nt) stage(cur ^ 1, kbeg + (t + 1) * 64);
    bf16x8 af[MR][2], bw[NR][2];
#pragma unroll
    for (int m = 0; m < MR; m++)
#pragma unroll
      for (int kk = 0; kk < 2; kk++) {
        const int row = wr * (BM/2) + m * 16 + lr;
        af[m][kk] = *(const bf16x8*)&sA[cur][row * 64 + (((kk*4 + lg) ^ (lr & 7)) * 8)];
      }
#pragma unroll
    for (int n = 0; n < NR; n++)
#pragma unroll
      for (int kk = 0; kk < 2; kk++) {
        const int row = wc * (BN/2) + n * 16 + lr;
        bw[n][kk] = *(const bf16x8*)&sB[cur][row * 64 + (((kk*4 + lg) ^ (lr & 7)) * 8)];
      }
#pragma unroll
    for (int kk = 0; kk < 2; kk++)
#pragma unroll
      for (int m = 0; m < MR; m++)
#pragma unroll
        for (int n = 0; n < NR; n++)
          acc[m][n] = __builtin_amdgcn_mfma_f32_16x16x32_bf16(af[m][kk], bw[n][kk], acc[m][n], 0, 0, 0);
    __syncthreads();
    cur ^= 1;
  }

#pragma unroll
  for (int m = 0; m < MR; m++) {
    const long rbase = row0 + wr * (BM/2) + m * 16 + lg * 4;
#pragma unroll
    for (int n = 0; n < NR; n++) {
      const long c = col0 + wc * (BN/2) + n * 16 + lr;
      const float bv = (EPI == 3 && kz) ? 0.f : bias[c];
#pragma unroll
      for (int j = 0; j < 4; j++) {
        const long r = rbase + j;
        float val = acc[m][n][j] + bv;
        if (EPI == 0) {
          const int part = (int)(c >> 8);
          const int cc = (int)(c & 255);
          const int h = cc >> 5, hd = cc & 31;
          const int bi = (int)(r & 3);
          const int s = (int)(r >> 2);
          const int bh = bi * HH + h;
          // q scale: (1/sqrt(32)) * 2*log2(e)  (activation uses exp2 directly)
          if (part == 0) val *= 0.51006972771029396f;
          size_t idx;
          if (part == 2) {  // V interleaved: [bh][s/8][hd][s%8]
            idx = (size_t)2 * (MM * DD) + (size_t)bh * (SS * HDD)
                + (size_t)(s >> 3) * (HDD * 8) + hd * 8 + (s & 7);
          } else {          // Q/K: [bh][s][hd]
            idx = (size_t)part * (MM * DD) + ((size_t)bh * SS + s) * HDD + hd;
          }
          ((short*)out)[idx] = (short)f2bf(val);
        } else if (EPI == 1) {
          ((float*)out)[(size_t)r * N + c] = val;
        } else if (EPI == 2) {
          ((short*)out)[(size_t)r * N + c] = (short)f2bf(fmaxf(val, 0.f));
        } else {
          short* op = kz ? (short*)out2 : (short*)out;
          op[(size_t)r * N + c] = (short)f2bf(val);
        }
      }
    }
  }
}

// ---------------- fused tanh-relu attention ----------------
// 32x32x16 MFMA, P fully in-register via cvt_pk + permlane32_swap.
// PV computed as O = mfma(A=P, B=V): V stored interleaved [s/8][d][s%8], so
// each 16-key B-frag is ONE 16B vector load. XCD-coherent flat grid (1024):
// all 32 blocks of a (b,h) land on xcd = bh%8. 4 waves x 32 q; split-K x2;
// bf16 partials into stacked A' (8192 x 512), consumed by K=512 out_proj.
__global__ __launch_bounds__(256, 4)
void attn_kernel(const short* __restrict__ Qb, const short* __restrict__ Kb,
                 const short* __restrict__ Vb, short* __restrict__ Aout)
{
  const int tid = threadIdx.x;
  const int l = tid & 63, w = tid >> 6;
  const int q32 = l & 31, hf = l >> 5;        // lane col, lane half
  const int i = blockIdx.x;                   // 0..1023
  const int j = i >> 3;                       // 0..127 (per-XCD serial)
  const int p = (i & 7) + 8 * (j >> 5);       // bh: fixed residue mod 8
  const int rem = j & 31;
  const int q0 = (rem >> 1) * 128 + w * 32;   // q-block 0..15
  const int kz = rem & 1;                     // key half
  const int kbeg = kz * (SS / 2);
  const int kend = kbeg + SS / 2;
  const size_t base = (size_t)p * SS * HDD;
  const short* Q  = Qb + base;
  const short* Kp = Kb + base;
  const short* Vp = Vb + base;                // interleaved [s/8][d=32][s%8]

  // Q frags (B operand of QK^T): lane holds Q[q0+q32][kdim], slot k = hf*8+j
  const short* qrow = &Q[(size_t)(q0 + q32) * HDD];
  const bf16x8 qf0 = *(const bf16x8*)&qrow[hf * 8];        // kdim 0..15
  const bf16x8 qf1 = *(const bf16x8*)&qrow[16 + hf * 8];   // kdim 16..31

  const f32x16 fzero = {};
  f32x16 accA = {}, accB = {};   // O[q][d]: col=q32 is d, row q=(r&3)+8*(r>>2)+4*hf

  auto loadK = [&](int t0, bf16x8* kf) {
    const short* kr = &Kp[(size_t)(t0 + q32) * HDD];
    kf[0] = *(const bf16x8*)&kr[hf * 8];
    kf[1] = *(const bf16x8*)&kr[16 + hf * 8];
  };
  // V B-frag f: slot (hf,e) = V[t0 + f*16 + hf*8 + e][d=q32]; in the
  // interleaved layout that is 8 contiguous shorts at group (t0>>3)+2f+hf.
  auto loadV = [&](int t0, bf16x8* vf) {
    const short* vb = &Vp[(size_t)((t0 >> 3) + hf) * (HDD * 8) + q32 * 8];
    vf[0] = *(const bf16x8*)&vb[0];
    vf[1] = *(const bf16x8*)&vb[2 * (HDD * 8)];
  };

  auto step = [&](const bf16x8* kf, const bf16x8* vf, f32x16& acc) {
    // scores D[key][q] over kdim=32 (pre-scaled by 2log2e/sqrt(32))
    f32x16 s = __builtin_amdgcn_mfma_f32_32x32x16_bf16(kf[0], qf0, fzero, 0, 0, 0);
    s = __builtin_amdgcn_mfma_f32_32x32x16_bf16(kf[1], qf1, s, 0, 0, 0);
    // relu(tanh(x)) = max(0, 1 - 2/(exp2(s)+1))
    float pv[16];
#pragma unroll
    for (int r = 0; r < 16; r++) {
      const float e = __builtin_amdgcn_exp2f(s[r]);
      pv[r] = fmaxf(1.f - 2.f * __builtin_amdgcn_rcpf(e + 1.f), 0.f);
    }
    unsigned X0 = pk2(pv[0], pv[1]),   X1 = pk2(pv[2], pv[3]);
    unsigned X2 = pk2(pv[4], pv[5]),   X3 = pk2(pv[6], pv[7]);
    unsigned X4 = pk2(pv[8], pv[9]),   X5 = pk2(pv[10], pv[11]);
    unsigned X6 = pk2(pv[12], pv[13]), X7 = pk2(pv[14], pv[15]);
    uint2v r02 = __builtin_amdgcn_permlane32_swap(X0, X2, false, false);
    uint2v r13 = __builtin_amdgcn_permlane32_swap(X1, X3, false, false);
    uint2v r46 = __builtin_amdgcn_permlane32_swap(X4, X6, false, false);
    uint2v r57 = __builtin_amdgcn_permlane32_swap(X5, X7, false, false);
    // P frags: lane q32 holds keys (slot k = 16f + hf*8 + e) -- valid A-frag
    const uint4v f0 = { r02[0], r13[0], r02[1], r13[1] };
    const uint4v f1 = { r46[0], r57[0], r46[1], r57[1] };
    const bf16x8 pa0 = __builtin_bit_cast(bf16x8, f0);
    const bf16x8 pa1 = __builtin_bit_cast(bf16x8, f1);
    // O[q][d] += P[q][k] * V[k][d]
    acc = __builtin_amdgcn_mfma_f32_32x32x16_bf16(pa0, vf[0], acc, 0, 0, 0);
    acc = __builtin_amdgcn_mfma_f32_32x32x16_bf16(pa1, vf[1], acc, 0, 0, 0);
  };

  bf16x8 kA[2], vA[2], kB[2], vB[2];
  loadK(kbeg, kA); loadV(kbeg, vA);
  for (int t0 = kbeg; t0 < kend; t0 += 64) {
    loadK(t0 + 32, kB); loadV(t0 + 32, vB);
    step(kA, vA, accA);
    const int tn = (t0 + 64 < kend) ? t0 + 64 : kbeg;
    loadK(tn, kA); loadV(tn, vA);
    step(kB, vB, accB);
  }

  const int bi = p >> 3, hh = p & 7;
  // A' row = s*BB+bi, K-stride 512; this lane owns column d = q32
  const size_t colo = (size_t)kz * DD + (size_t)hh * HDD + q32;
#pragma unroll
  for (int r = 0; r < 16; r++) {
    const int crow = (r & 3) + 8 * (r >> 2) + 4 * hf;
    Aout[((size_t)(q0 + crow) * BB + bi) * (2 * DD) + colo] =
        (short)f2bf(accA[r] + accB[r]);
  }
}

// ---------------- launch ----------------
extern "C" void kernel_launch(void* const* d_in, const int* in_sizes, int n_in,
                              void* d_out, int out_size, void* d_ws, size_t ws_size,
                              hipStream_t stream) {
  const float* features   = (const float*)d_in[0];
  const float* ln_g       = (const float*)d_in[1];
  const float* ln_b       = (const float*)d_in[2];
  const float* in_proj_w  = (const float*)d_in[3];
  const float* in_proj_b  = (const float*)d_in[4];
  const float* out_proj_w = (const float*)d_in[5];
  const float* out_proj_b = (const float*)d_in[6];
  const float* w1 = (const float*)d_in[7];
  const float* b1 = (const float*)d_in[8];
  const float* w2 = (const float*)d_in[9];
  const float* b2 = (const float*)d_in[10];

  char* ws = (char*)d_ws;
  const size_t MB = 1024 * 1024;
  // [0,8)   lnx_f
  // [8,12)  lnx_b
  // [12,24) qkv (q,k,vI)   -> [12,16) ffb ; [16,20) ffp1 ; [20,24) r1_b
  //         (proj f32 occupies [12,20) between out_proj and r1 LN)
  // [24,32) A' (attn stacked partials, bf16 8192x512) -> r1_f (after out_proj)
  // [32,64) h1
  // [64,~)  weights
  float* lnx_f  = (float*)(ws + 0);
  short* lnx_b  = (short*)(ws + 8 * MB);
  short* qkv    = (short*)(ws + 12 * MB);
  short* aprt   = (short*)(ws + 24 * MB);   // A' stacked attn partials (8MB)
  float* proj   = (float*)(ws + 12 * MB);
  short* r1_b   = (short*)(ws + 20 * MB);
  float* r1_f   = (float*)(ws + 24 * MB);
  short* h1     = (short*)(ws + 32 * MB);
  short* ffb    = (short*)(ws + 12 * MB);   // ff partial 0, bf16 (4MB)
  short* ffp1   = (short*)(ws + 16 * MB);   // ff partial 1, bf16 (4MB)
  short* wqkv_b = (short*)(ws + 64 * MB);
  short* wout_b = wqkv_b + 768 * 256;
  short* w1_b   = wout_b + 256 * 256;
  short* w2_b   = w1_b + 2048 * 256;

  // 1) weight converts + ln_x = LN(features), one launch
  cvt_ln<<<dim3(2048, 5), 256, 0, stream>>>(in_proj_w, out_proj_w, w1, w2,
                                            wqkv_b, wout_b, w1_b, w2_b,
                                            features, ln_g, ln_b, lnx_f, lnx_b);

  // 2) qkv = ln_x @ in_proj_w^T + b  (q/k per-(b,h) [s][hd], v interleaved)
  gemm_bt<0, 128, 64, 0><<<dim3(12, 64, 1), 256, 0, stream>>>(lnx_b, wqkv_b, in_proj_b, qkv, nullptr, 256, 768, 256);

  // 3) attention (relu(tanh(qk^T)) @ v), split-K x2, XCD-coherent block map
  attn_kernel<<<dim3(1024, 1, 1), 256, 0, stream>>>(qkv, qkv + 2097152, qkv + 2 * 2097152, aprt);

  // 4) proj = (sum of A' partials) @ out_proj_w^T + b  [K=512, W wraps mod 256]
  gemm_bt<1, 64, 64, 256><<<dim3(4, 128, 1), 256, 0, stream>>>(aprt, wout_b, out_proj_b, proj, nullptr, 512, 256, 512);

  // 5) r1 = LN(ln_x + proj)
  ln_kernel<2, 1, 1, 0><<<2048, 256, 0, stream>>>(lnx_f, proj, nullptr, ln_g, ln_b, r1_f, r1_b);

  // 6) h1 = relu(r1 @ w1^T + b1)  [128x128 tile: 32 MFMA per barrier-pair]
  gemm_bt<2, 128, 128, 0><<<dim3(16, 64, 1), 256, 0, stream>>>(r1_b, w1_b, b1, h1, nullptr, 256, 2048, 256);

  // 7) ff = h1 @ w2^T + b2  (split-K x2: bf16 partials in ffb, ffp1)
  gemm_bt<3, 128, 64, 0><<<dim3(4, 64, 2), 256, 0, stream>>>(h1, w2_b, b2, ffb, ffp1, 2048, 256, 1024);

  // 8) out = LN(r1 + ff0 + ff1)   (bf16 partial inputs)
  ln_kernel<3, 1, 0, 1><<<2048, 256, 0, stream>>>(r1_f, ffb, ffp1, ln_g, ln_b, (float*)d_out, nullptr);
}